// Round 1
// baseline (178.872 us; speedup 1.0000x reference)
//
#include <hip/hip_runtime.h>
#include <hip/hip_bf16.h>

// SpherePool: out[bt, o, c] = max_{k<7} tensor[bt, index[o,k], c]
// B*T = 16, N = 40962, C = 256, N_OUT = 10242, K = 7.
// Memory-bound gather + row-max. One output row (256 f32) = 64 lanes x float4.
// Block = 256 threads = 4 rows. Rows ordered o-fastest so concurrent blocks
// share the same 42 MB bt-slice in L3.

#define N_IN    40962
#define N_OUT   10242
#define KGATH   7
#define C_VEC   64          // 256 f32 channels / 4 per float4
#define ROWS_PER_BLOCK 4

__global__ __launch_bounds__(256) void spherepool_kernel(
    const float4* __restrict__ tensor,   // [BT][N_IN][64] float4
    const int*    __restrict__ index,    // [N_OUT][7]
    float4*       __restrict__ out)      // [BT][N_OUT][64] float4
{
    const int row  = blockIdx.x * ROWS_PER_BLOCK + (threadIdx.x >> 6);
    const int lane = threadIdx.x & 63;

    const int bt = row / N_OUT;
    const int o  = row - bt * N_OUT;

    const int* idx = index + o * KGATH;
    const float4* __restrict__ base = tensor + (size_t)bt * N_IN * C_VEC;

    // 7 independent gathers -> ILP; each wave access is 64x16B contiguous.
    float4 v0 = base[(size_t)idx[0] * C_VEC + lane];
    float4 v1 = base[(size_t)idx[1] * C_VEC + lane];
    float4 v2 = base[(size_t)idx[2] * C_VEC + lane];
    float4 v3 = base[(size_t)idx[3] * C_VEC + lane];
    float4 v4 = base[(size_t)idx[4] * C_VEC + lane];
    float4 v5 = base[(size_t)idx[5] * C_VEC + lane];
    float4 v6 = base[(size_t)idx[6] * C_VEC + lane];

    float4 m;
    m.x = fmaxf(fmaxf(fmaxf(v0.x, v1.x), fmaxf(v2.x, v3.x)), fmaxf(fmaxf(v4.x, v5.x), v6.x));
    m.y = fmaxf(fmaxf(fmaxf(v0.y, v1.y), fmaxf(v2.y, v3.y)), fmaxf(fmaxf(v4.y, v5.y), v6.y));
    m.z = fmaxf(fmaxf(fmaxf(v0.z, v1.z), fmaxf(v2.z, v3.z)), fmaxf(fmaxf(v4.z, v5.z), v6.z));
    m.w = fmaxf(fmaxf(fmaxf(v0.w, v1.w), fmaxf(v2.w, v3.w)), fmaxf(fmaxf(v4.w, v5.w), v6.w));

    out[(size_t)row * C_VEC + lane] = m;
}

extern "C" void kernel_launch(void* const* d_in, const int* in_sizes, int n_in,
                              void* d_out, int out_size, void* d_ws, size_t ws_size,
                              hipStream_t stream) {
    const float4* tensor = (const float4*)d_in[0];
    const int*    index  = (const int*)d_in[1];
    float4*       out    = (float4*)d_out;

    const int total_rows = 16 * N_OUT;               // 163872, divisible by 4
    const int blocks = total_rows / ROWS_PER_BLOCK;  // 40968

    spherepool_kernel<<<blocks, 256, 0, stream>>>(tensor, index, out);
}